// Round 3
// baseline (1303.407 us; speedup 1.0000x reference)
//
#include <hip/hip_runtime.h>

#define Bb 8
#define Nn 20000
#define Cc 128
#define Kk 64
#define Ee 320000

#define WAVES_PER_BLOCK 4
#define NODES_PER_WAVE 4

// ---------------------------------------------------------------------------
// Kernel 1: per-node MLP -> softmax -> mask  => S (B,N,K) f32
// wave-per-quad-of-nodes; W1 (32KB) + W2 (16KB) staged in LDS.
// ---------------------------------------------------------------------------
__global__ __launch_bounds__(256) void k_compute_S(
    const float* __restrict__ x, const int* __restrict__ mask,
    const float* __restrict__ W1, const float* __restrict__ b1,
    const float* __restrict__ W2, const float* __restrict__ b2,
    float* __restrict__ S)
{
    __shared__ float W1s[Cc * Kk];                                  // 32 KB
    __shared__ float W2s[Kk * Kk];                                  // 16 KB
    __shared__ __align__(16) float xs[WAVES_PER_BLOCK][NODES_PER_WAVE * Cc]; // 8 KB
    __shared__ __align__(16) float hs[WAVES_PER_BLOCK][NODES_PER_WAVE * Kk]; // 4 KB

    const int tid = threadIdx.x;
    for (int i = tid; i < Cc * Kk; i += 256) W1s[i] = W1[i];
    for (int i = tid; i < Kk * Kk; i += 256) W2s[i] = W2[i];
    __syncthreads();

    const int lane = tid & 63;
    const int wid  = tid >> 6;
    const float b1k = b1[lane];
    const float b2l = b2[lane];

    const int quadsPerBatch = Nn / NODES_PER_WAVE;        // 5000
    const int totalQuads = Bb * quadsPerBatch;            // 40000
    const int gwave  = blockIdx.x * WAVES_PER_BLOCK + wid;
    const int nwaves = gridDim.x * WAVES_PER_BLOCK;

    for (int q = gwave; q < totalQuads; q += nwaves) {
        const int b  = q / quadsPerBatch;
        const int n0 = (q % quadsPerBatch) * NODES_PER_WAVE;
        const size_t xbase = ((size_t)b * Nn + n0) * Cc;

        // stage 4 node rows of x (512 contiguous floats) into this wave's LDS
        {
            const float4* xg = (const float4*)(x + xbase);
            float4* xl = (float4*)xs[wid];
            #pragma unroll
            for (int i = 0; i < 2; ++i) xl[lane + 64 * i] = xg[lane + 64 * i];
        }

        // h = relu(x @ W1 + b1); lane owns column k=lane, 4 nodes at once
        float h[NODES_PER_WAVE];
        #pragma unroll
        for (int i = 0; i < NODES_PER_WAVE; ++i) h[i] = b1k;

        for (int c0 = 0; c0 < Cc; c0 += 4) {
            float4 xv[NODES_PER_WAVE];
            #pragma unroll
            for (int i = 0; i < NODES_PER_WAVE; ++i)
                xv[i] = *(const float4*)&xs[wid][i * Cc + c0];
            #pragma unroll
            for (int j = 0; j < 4; ++j) {
                const float w1 = W1s[(c0 + j) * Kk + lane];
                #pragma unroll
                for (int i = 0; i < NODES_PER_WAVE; ++i) {
                    const float xj = (j == 0) ? xv[i].x : (j == 1) ? xv[i].y
                                    : (j == 2) ? xv[i].z : xv[i].w;
                    h[i] = fmaf(xj, w1, h[i]);
                }
            }
        }
        #pragma unroll
        for (int i = 0; i < NODES_PER_WAVE; ++i)
            hs[wid][i * Kk + lane] = fmaxf(h[i], 0.f);

        // logits = h @ W2 + b2; lane owns column l=lane
        float a[NODES_PER_WAVE];
        #pragma unroll
        for (int i = 0; i < NODES_PER_WAVE; ++i) a[i] = b2l;

        for (int k0 = 0; k0 < Kk; k0 += 4) {
            float4 hv[NODES_PER_WAVE];
            #pragma unroll
            for (int i = 0; i < NODES_PER_WAVE; ++i)
                hv[i] = *(const float4*)&hs[wid][i * Kk + k0];
            #pragma unroll
            for (int j = 0; j < 4; ++j) {
                const float w2 = W2s[(k0 + j) * Kk + lane];
                #pragma unroll
                for (int i = 0; i < NODES_PER_WAVE; ++i) {
                    const float hj = (j == 0) ? hv[i].x : (j == 1) ? hv[i].y
                                    : (j == 2) ? hv[i].z : hv[i].w;
                    a[i] = fmaf(hj, w2, a[i]);
                }
            }
        }

        // softmax over the 64 lanes (K dim), apply node mask, store S row
        #pragma unroll
        for (int i = 0; i < NODES_PER_WAVE; ++i) {
            float mx = a[i];
            #pragma unroll
            for (int off = 32; off >= 1; off >>= 1)
                mx = fmaxf(mx, __shfl_xor(mx, off));
            const float e = __expf(a[i] - mx);
            float sm = e;
            #pragma unroll
            for (int off = 32; off >= 1; off >>= 1)
                sm += __shfl_xor(sm, off);
            const float mv = (mask[(size_t)b * Nn + n0 + i] > 0) ? 1.f : 0.f;
            S[((size_t)b * Nn + n0 + i) * Kk + lane] = e / sm * mv;
        }
    }
}

// ---------------------------------------------------------------------------
// Kernel 2: pmask (B,K) — 1 iff any mask>0 in the batch row
// ---------------------------------------------------------------------------
__global__ __launch_bounds__(256) void k_pmask(const int* __restrict__ mask,
                                               float* __restrict__ pmask)
{
    __shared__ int s_any;
    if (threadIdx.x == 0) s_any = 0;
    __syncthreads();
    const int b = blockIdx.x;
    int any = 0;
    for (int i = threadIdx.x; i < Nn; i += blockDim.x)
        any |= (mask[(size_t)b * Nn + i] > 0) ? 1 : 0;
    if (any) atomicOr(&s_any, 1);
    __syncthreads();
    if (threadIdx.x < Kk)
        pmask[(size_t)b * Kk + threadIdx.x] = s_any ? 1.f : 0.f;
}

// ---------------------------------------------------------------------------
// Kernel 3 (fused): pooled_adj[b,k,l] = sum_e w_e * S[b,v_e,k] * S[b,u_e,l]
// wave-per-64-edge-group, ballot-compact valid edges, 4-edge ILP batches,
// rank-1 updates into per-lane register column acc[64]; LDS block reduce.
// ---------------------------------------------------------------------------
__global__ __launch_bounds__(256) void k_pooled_edges(
    const int* __restrict__ ei, const float* __restrict__ ew,
    const int* __restrict__ mask, const float* __restrict__ S,
    float* __restrict__ pooled)
{
    __shared__ float tile[Kk * Kk];   // 16 KB
    const int tid  = threadIdx.x;
    const int lane = tid & 63;
    const int wid  = tid >> 6;

    for (int i = tid; i < Kk * Kk; i += 256) tile[i] = 0.f;
    __syncthreads();

    const int b    = blockIdx.x >> 8;          // 256 blocks per batch
    const int slot = blockIdx.x & 255;
    const int groupsPerBatch = Ee / 64;        // 5000
    const size_t eib = (size_t)b * 2 * Ee;
    const float* Sb  = S + (size_t)b * Nn * Kk;
    const int*   mb  = mask + (size_t)b * Nn;

    float acc[Kk];
    #pragma unroll
    for (int k = 0; k < Kk; ++k) acc[k] = 0.f;

    const int wavesPerBatch = 256 * WAVES_PER_BLOCK;   // 1024
    for (int g = slot * WAVES_PER_BLOCK + wid; g < groupsPerBatch; g += wavesPerBatch) {
        const int e0 = g * 64;
        const int   u = ei[eib + e0 + lane];           // int32 on device
        const int   v = ei[eib + Ee + e0 + lane];
        const float w = ew[(size_t)b * Ee + e0 + lane];
        const bool valid = (mb[u] > 0) && (mb[v] > 0) && (w != 0.f);

        unsigned long long vm = __ballot(valid);
        while (vm) {
            // peel up to 4 valid edges; pad with weight 0 (lane-0 indices, safe)
            int t0 = __builtin_ctzll(vm); vm &= vm - 1;
            int t1 = 0, t2 = 0, t3 = 0;
            float w1f = 0.f, w2f = 0.f, w3f = 0.f;
            if (vm) { t1 = __builtin_ctzll(vm); vm &= vm - 1; w1f = 1.f; }
            if (vm) { t2 = __builtin_ctzll(vm); vm &= vm - 1; w2f = 1.f; }
            if (vm) { t3 = __builtin_ctzll(vm); vm &= vm - 1; w3f = 1.f; }

            const int   u0 = __shfl(u, t0), v0 = __shfl(v, t0);
            const int   u1 = __shfl(u, t1), v1 = __shfl(v, t1);
            const int   u2 = __shfl(u, t2), v2 = __shfl(v, t2);
            const int   u3 = __shfl(u, t3), v3 = __shfl(v, t3);
            const float wt0 = __shfl(w, t0);
            const float wt1 = __shfl(w, t1) * w1f;
            const float wt2 = __shfl(w, t2) * w2f;
            const float wt3 = __shfl(w, t3) * w3f;

            // 8 independent coalesced gathers (256B each) in flight
            const float su0 = Sb[(size_t)u0 * Kk + lane];
            const float sv0 = Sb[(size_t)v0 * Kk + lane];
            const float su1 = Sb[(size_t)u1 * Kk + lane];
            const float sv1 = Sb[(size_t)v1 * Kk + lane];
            const float su2 = Sb[(size_t)u2 * Kk + lane];
            const float sv2 = Sb[(size_t)v2 * Kk + lane];
            const float su3 = Sb[(size_t)u3 * Kk + lane];
            const float sv3 = Sb[(size_t)v3 * Kk + lane];

            const float ws0 = wt0 * su0;
            const float ws1 = wt1 * su1;
            const float ws2 = wt2 * su2;
            const float ws3 = wt3 * su3;

            #pragma unroll
            for (int k = 0; k < Kk; ++k) {
                acc[k] = fmaf(__shfl(sv0, k), ws0, acc[k]);
                acc[k] = fmaf(__shfl(sv1, k), ws1, acc[k]);
                acc[k] = fmaf(__shfl(sv2, k), ws2, acc[k]);
                acc[k] = fmaf(__shfl(sv3, k), ws3, acc[k]);
            }
        }
    }

    // block reduce: 4 waves -> LDS tile (row k, col lane)
    #pragma unroll
    for (int k = 0; k < Kk; ++k)
        atomicAdd(&tile[k * Kk + lane], acc[k]);
    __syncthreads();

    float* pb = pooled + (size_t)b * Kk * Kk;
    for (int i = tid; i < Kk * Kk; i += 256)
        atomicAdd(&pb[i], tile[i]);
}

// ---------------------------------------------------------------------------
// Kernel 4: pfeat[b,k,c] = sum_n S[b,n,k] * x[b,n,c]
// thread owns (k, 32 c's) in registers; 8-node LDS staging; atomic epilogue
// ---------------------------------------------------------------------------
#define PF_NODES 8
__global__ __launch_bounds__(256) void k_pfeat(
    const float* __restrict__ x, const float* __restrict__ S,
    float* __restrict__ pfeat)
{
    __shared__ __align__(16) float xsh[PF_NODES * Cc];  // 4 KB
    __shared__ __align__(16) float ssh[PF_NODES * Kk];  // 2 KB
    const int tid = threadIdx.x;
    const int k   = tid & 63;
    const int c0  = (tid >> 6) * 32;
    const int b   = blockIdx.x & 7;
    const int bslot = blockIdx.x >> 3;
    const int blocksPerBatch = gridDim.x >> 3;
    const int chunks = Nn / PF_NODES;                    // 2500

    float acc[32];
    #pragma unroll
    for (int j = 0; j < 32; ++j) acc[j] = 0.f;

    for (int ch = bslot; ch < chunks; ch += blocksPerBatch) {
        const size_t nb = (size_t)b * Nn + (size_t)ch * PF_NODES;
        __syncthreads();
        {
            const float4* xg = (const float4*)(x + nb * Cc);
            const float4* sg = (const float4*)(S + nb * Kk);
            float4* xl = (float4*)xsh;
            float4* sl = (float4*)ssh;
            xl[tid] = xg[tid];                           // 256 float4 = 8*128
            if (tid < 128) sl[tid] = sg[tid];            // 128 float4 = 8*64
        }
        __syncthreads();
        #pragma unroll
        for (int nn = 0; nn < PF_NODES; ++nn) {
            const float s = ssh[nn * Kk + k];
            #pragma unroll
            for (int j4 = 0; j4 < 8; ++j4) {
                const float4 xv = *(const float4*)&xsh[nn * Cc + c0 + j4 * 4];
                acc[j4 * 4 + 0] = fmaf(s, xv.x, acc[j4 * 4 + 0]);
                acc[j4 * 4 + 1] = fmaf(s, xv.y, acc[j4 * 4 + 1]);
                acc[j4 * 4 + 2] = fmaf(s, xv.z, acc[j4 * 4 + 2]);
                acc[j4 * 4 + 3] = fmaf(s, xv.w, acc[j4 * 4 + 3]);
            }
        }
    }
    float* pf = pfeat + (size_t)b * Kk * Cc + (size_t)k * Cc + c0;
    #pragma unroll
    for (int j = 0; j < 32; ++j) atomicAdd(&pf[j], acc[j]);
}

// ---------------------------------------------------------------------------
extern "C" void kernel_launch(void* const* d_in, const int* in_sizes, int n_in,
                              void* d_out, int out_size, void* d_ws, size_t ws_size,
                              hipStream_t stream)
{
    const float* x    = (const float*)d_in[0];
    const int*   ei   = (const int*)d_in[1];     // int64 in reference -> int32 on device
    const float* ew   = (const float*)d_in[2];
    const int*   mask = (const int*)d_in[3];
    const float* W1   = (const float*)d_in[4];
    const float* b1   = (const float*)d_in[5];
    const float* W2   = (const float*)d_in[6];
    const float* b2   = (const float*)d_in[7];

    float* out    = (float*)d_out;
    float* pfeat  = out;                                               // B*K*C
    float* pooled = out + (size_t)Bb * Kk * Cc;                        // B*K*K
    float* pmask  = out + (size_t)Bb * Kk * Cc + (size_t)Bb * Kk * Kk; // B*K

    float* S = (float*)d_ws;                                           // B*N*K f32 = 40.96 MB

    hipMemsetAsync(d_out, 0, sizeof(float) * (size_t)out_size, stream);

    k_compute_S<<<1024, 256, 0, stream>>>(x, mask, W1, b1, W2, b2, S);
    k_pmask<<<Bb, 256, 0, stream>>>(mask, pmask);
    k_pooled_edges<<<2048, 256, 0, stream>>>(ei, ew, mask, S, pooled);
    k_pfeat<<<1024, 256, 0, stream>>>(x, S, pfeat);
}

// Round 4
// 528.636 us; speedup vs baseline: 2.4656x; 2.4656x over previous
//
#include <hip/hip_runtime.h>

#define Bb 8
#define Nn 20000
#define Cc 128
#define Kk 64
#define Ee 320000

#define WAVES_PER_BLOCK 4
#define NODES_PER_WAVE 4

typedef __attribute__((ext_vector_type(8))) short bf16x8;
typedef __attribute__((ext_vector_type(16))) float f32x16;

__device__ __forceinline__ unsigned short f2bf(float f) {
    unsigned int u = __float_as_uint(f);
    u += 0x7FFFu + ((u >> 16) & 1u);          // round-to-nearest-even
    return (unsigned short)(u >> 16);
}

// ---------------------------------------------------------------------------
// Kernel 1: per-node MLP -> softmax -> mask  => S (B,N,K) f32  (unchanged)
// ---------------------------------------------------------------------------
__global__ __launch_bounds__(256) void k_compute_S(
    const float* __restrict__ x, const int* __restrict__ mask,
    const float* __restrict__ W1, const float* __restrict__ b1,
    const float* __restrict__ W2, const float* __restrict__ b2,
    float* __restrict__ S)
{
    __shared__ float W1s[Cc * Kk];
    __shared__ float W2s[Kk * Kk];
    __shared__ __align__(16) float xs[WAVES_PER_BLOCK][NODES_PER_WAVE * Cc];
    __shared__ __align__(16) float hs[WAVES_PER_BLOCK][NODES_PER_WAVE * Kk];

    const int tid = threadIdx.x;
    for (int i = tid; i < Cc * Kk; i += 256) W1s[i] = W1[i];
    for (int i = tid; i < Kk * Kk; i += 256) W2s[i] = W2[i];
    __syncthreads();

    const int lane = tid & 63;
    const int wid  = tid >> 6;
    const float b1k = b1[lane];
    const float b2l = b2[lane];

    const int quadsPerBatch = Nn / NODES_PER_WAVE;
    const int totalQuads = Bb * quadsPerBatch;
    const int gwave  = blockIdx.x * WAVES_PER_BLOCK + wid;
    const int nwaves = gridDim.x * WAVES_PER_BLOCK;

    for (int q = gwave; q < totalQuads; q += nwaves) {
        const int b  = q / quadsPerBatch;
        const int n0 = (q % quadsPerBatch) * NODES_PER_WAVE;
        const size_t xbase = ((size_t)b * Nn + n0) * Cc;

        {
            const float4* xg = (const float4*)(x + xbase);
            float4* xl = (float4*)xs[wid];
            #pragma unroll
            for (int i = 0; i < 2; ++i) xl[lane + 64 * i] = xg[lane + 64 * i];
        }

        float h[NODES_PER_WAVE];
        #pragma unroll
        for (int i = 0; i < NODES_PER_WAVE; ++i) h[i] = b1k;

        for (int c0 = 0; c0 < Cc; c0 += 4) {
            float4 xv[NODES_PER_WAVE];
            #pragma unroll
            for (int i = 0; i < NODES_PER_WAVE; ++i)
                xv[i] = *(const float4*)&xs[wid][i * Cc + c0];
            #pragma unroll
            for (int j = 0; j < 4; ++j) {
                const float w1 = W1s[(c0 + j) * Kk + lane];
                #pragma unroll
                for (int i = 0; i < NODES_PER_WAVE; ++i) {
                    const float xj = (j == 0) ? xv[i].x : (j == 1) ? xv[i].y
                                    : (j == 2) ? xv[i].z : xv[i].w;
                    h[i] = fmaf(xj, w1, h[i]);
                }
            }
        }
        #pragma unroll
        for (int i = 0; i < NODES_PER_WAVE; ++i)
            hs[wid][i * Kk + lane] = fmaxf(h[i], 0.f);

        float a[NODES_PER_WAVE];
        #pragma unroll
        for (int i = 0; i < NODES_PER_WAVE; ++i) a[i] = b2l;

        for (int k0 = 0; k0 < Kk; k0 += 4) {
            float4 hv[NODES_PER_WAVE];
            #pragma unroll
            for (int i = 0; i < NODES_PER_WAVE; ++i)
                hv[i] = *(const float4*)&hs[wid][i * Kk + k0];
            #pragma unroll
            for (int j = 0; j < 4; ++j) {
                const float w2 = W2s[(k0 + j) * Kk + lane];
                #pragma unroll
                for (int i = 0; i < NODES_PER_WAVE; ++i) {
                    const float hj = (j == 0) ? hv[i].x : (j == 1) ? hv[i].y
                                    : (j == 2) ? hv[i].z : hv[i].w;
                    a[i] = fmaf(hj, w2, a[i]);
                }
            }
        }

        #pragma unroll
        for (int i = 0; i < NODES_PER_WAVE; ++i) {
            float mx = a[i];
            #pragma unroll
            for (int off = 32; off >= 1; off >>= 1)
                mx = fmaxf(mx, __shfl_xor(mx, off));
            const float e = __expf(a[i] - mx);
            float sm = e;
            #pragma unroll
            for (int off = 32; off >= 1; off >>= 1)
                sm += __shfl_xor(sm, off);
            const float mv = (mask[(size_t)b * Nn + n0 + i] > 0) ? 1.f : 0.f;
            S[((size_t)b * Nn + n0 + i) * Kk + lane] = e / sm * mv;
        }
    }
}

// ---------------------------------------------------------------------------
// Kernel 2: pmask (unchanged)
// ---------------------------------------------------------------------------
__global__ __launch_bounds__(256) void k_pmask(const int* __restrict__ mask,
                                               float* __restrict__ pmask)
{
    __shared__ int s_any;
    if (threadIdx.x == 0) s_any = 0;
    __syncthreads();
    const int b = blockIdx.x;
    int any = 0;
    for (int i = threadIdx.x; i < Nn; i += blockDim.x)
        any |= (mask[(size_t)b * Nn + i] > 0) ? 1 : 0;
    if (any) atomicOr(&s_any, 1);
    __syncthreads();
    if (threadIdx.x < Kk)
        pmask[(size_t)b * Kk + threadIdx.x] = s_any ? 1.f : 0.f;
}

// ---------------------------------------------------------------------------
// Kernel 3 (MFMA rewrite): pooled[b,k,l] = sum_e w_e * S[b,v_e,k] * S[b,u_e,l]
// = GEMM with edges as contraction dim. Per wave: compact valid edges into a
// private LDS ring; per 16-edge chunk gather 32 S-rows, convert to bf16 into
// fragment-layout LDS, 4x mfma_f32_32x32x16_bf16 accumulate 64x64 in regs.
// ---------------------------------------------------------------------------
__global__ __launch_bounds__(256) void k_pooled_edges(
    const int* __restrict__ ei, const float* __restrict__ ew,
    const int* __restrict__ mask, const float* __restrict__ S,
    float* __restrict__ pooled)
{
    __shared__ float tile[Kk * Kk];                 // 16 KB block-reduce tile
    __shared__ int   qu[4][128];                    // per-wave edge ring
    __shared__ int   qv[4][128];
    __shared__ float qw[4][128];
    __shared__ unsigned short AVb[4][1024];         // A frags: 2 kt-planes x 64 chunks x 8 bf16
    __shared__ unsigned short BUb[4][1024];         // B frags

    const int tid  = threadIdx.x;
    const int lane = tid & 63;
    const int wid  = tid >> 6;

    for (int i = tid; i < Kk * Kk; i += 256) tile[i] = 0.f;
    __syncthreads();

    const int b    = blockIdx.x >> 6;               // 64 blocks per batch
    const int slot = blockIdx.x & 63;
    const int groupsPerBatch = Ee / 64;             // 5000
    const size_t eib = (size_t)b * 2 * Ee;
    const float* Sb = S + (size_t)b * Nn * Kk;
    const int*   mb = mask + (size_t)b * Nn;

    int*   quw = qu[wid];
    int*   qvw = qv[wid];
    float* qww = qw[wid];
    unsigned short* AVw = AVb[wid];
    unsigned short* BUw = BUb[wid];

    f32x16 acc00 = 0.f, acc01 = 0.f, acc10 = 0.f, acc11 = 0.f;

    // element (feature f=lane, edge j) -> ushort idx in fragment layout:
    // (f>>5)*512 + (j>>3)*256 + (f&31)*8 + (j&7)
    const int wbase = (lane >> 5) * 512 + (lane & 31) * 8;

    auto process16 = [&](int hd) {
        asm volatile("s_waitcnt lgkmcnt(0)" ::: "memory");
        const int sl = (hd + (lane & 15)) & 127;
        const int   uu = quw[sl];
        const int   vv = qvw[sl];
        const float ww = qww[sl];
        float sv[16], su[16];
        #pragma unroll
        for (int j = 0; j < 16; ++j) {
            const int vj = __shfl(vv, j);
            const int uj = __shfl(uu, j);
            sv[j] = Sb[(size_t)vj * Kk + lane];     // coalesced row gather
            su[j] = Sb[(size_t)uj * Kk + lane];
        }
        #pragma unroll
        for (int j = 0; j < 16; ++j) {
            const float wj = __shfl(ww, j);
            const int ci = wbase + (j >> 3) * 256 + (j & 7);
            AVw[ci] = f2bf(wj * sv[j]);             // A'[k,e] = w * S[v,k]
            BUw[ci] = f2bf(su[j]);                  // B'[e,l] = S[u,l]
        }
        asm volatile("s_waitcnt lgkmcnt(0)" ::: "memory");
        const bf16x8* Af = (const bf16x8*)AVw;      // lane-contiguous 16B reads
        const bf16x8* Bf = (const bf16x8*)BUw;
        const bf16x8 a0 = Af[lane];
        const bf16x8 a1 = Af[64 + lane];
        const bf16x8 b0 = Bf[lane];
        const bf16x8 b1 = Bf[64 + lane];
        acc00 = __builtin_amdgcn_mfma_f32_32x32x16_bf16(a0, b0, acc00, 0, 0, 0);
        acc01 = __builtin_amdgcn_mfma_f32_32x32x16_bf16(a0, b1, acc01, 0, 0, 0);
        acc10 = __builtin_amdgcn_mfma_f32_32x32x16_bf16(a1, b0, acc10, 0, 0, 0);
        acc11 = __builtin_amdgcn_mfma_f32_32x32x16_bf16(a1, b1, acc11, 0, 0, 0);
    };

    int head = 0, count = 0;
    const int wslot = slot * 4 + wid;               // 0..255 within batch
    for (int g = wslot; g < groupsPerBatch; g += 256) {
        const int e0 = g * 64;
        const int   u = ei[eib + e0 + lane];
        const int   v = ei[eib + Ee + e0 + lane];
        const float w = ew[(size_t)b * Ee + e0 + lane];
        const bool valid = (mb[u] > 0) && (mb[v] > 0);
        const unsigned long long mk = __ballot(valid);
        const int myoff = __popcll(mk & ((1ull << lane) - 1ull));
        if (valid) {
            const int p = (head + count + myoff) & 127;
            quw[p] = u; qvw[p] = v; qww[p] = w;
        }
        count += (int)__popcll(mk);
        while (count >= 16) {
            process16(head);
            head = (head + 16) & 127;
            count -= 16;
        }
    }
    if (count > 0) {                                // pad tail chunk with w=0
        if (lane < 16 && lane >= count) {
            const int p = (head + lane) & 127;
            quw[p] = 0; qvw[p] = 0; qww[p] = 0.f;
        }
        process16(head);
    }

    // epilogue: regs -> LDS tile (verified 32x32 C/D mapping) -> global atomics
    const int rbase = 4 * (lane >> 5);
    const int col   = lane & 31;
    #pragma unroll
    for (int r = 0; r < 16; ++r) {
        const int row = (r & 3) + 8 * (r >> 2) + rbase;
        atomicAdd(&tile[row * Kk + col],              acc00[r]);
        atomicAdd(&tile[row * Kk + 32 + col],         acc01[r]);
        atomicAdd(&tile[(32 + row) * Kk + col],       acc10[r]);
        atomicAdd(&tile[(32 + row) * Kk + 32 + col],  acc11[r]);
    }
    __syncthreads();
    float* pb = pooled + (size_t)b * Kk * Kk;
    for (int i = tid; i < Kk * Kk; i += 256)
        atomicAdd(&pb[i], tile[i]);
}

// ---------------------------------------------------------------------------
// Kernel 4: pfeat (unchanged, R2 config)
// ---------------------------------------------------------------------------
#define PF_NODES 8
__global__ __launch_bounds__(256) void k_pfeat(
    const float* __restrict__ x, const float* __restrict__ S,
    float* __restrict__ pfeat)
{
    __shared__ __align__(16) float xsh[PF_NODES * Cc];
    __shared__ __align__(16) float ssh[PF_NODES * Kk];
    const int tid = threadIdx.x;
    const int k   = tid & 63;
    const int c0  = (tid >> 6) * 32;
    const int b   = blockIdx.x & 7;
    const int bslot = blockIdx.x >> 3;
    const int blocksPerBatch = gridDim.x >> 3;
    const int chunks = Nn / PF_NODES;

    float acc[32];
    #pragma unroll
    for (int j = 0; j < 32; ++j) acc[j] = 0.f;

    for (int ch = bslot; ch < chunks; ch += blocksPerBatch) {
        const size_t nb = (size_t)b * Nn + (size_t)ch * PF_NODES;
        __syncthreads();
        {
            const float4* xg = (const float4*)(x + nb * Cc);
            const float4* sg = (const float4*)(S + nb * Kk);
            float4* xl = (float4*)xsh;
            float4* sl = (float4*)ssh;
            xl[tid] = xg[tid];
            if (tid < 128) sl[tid] = sg[tid];
        }
        __syncthreads();
        #pragma unroll
        for (int nn = 0; nn < PF_NODES; ++nn) {
            const float s = ssh[nn * Kk + k];
            #pragma unroll
            for (int j4 = 0; j4 < 8; ++j4) {
                const float4 xv = *(const float4*)&xsh[nn * Cc + c0 + j4 * 4];
                acc[j4 * 4 + 0] = fmaf(s, xv.x, acc[j4 * 4 + 0]);
                acc[j4 * 4 + 1] = fmaf(s, xv.y, acc[j4 * 4 + 1]);
                acc[j4 * 4 + 2] = fmaf(s, xv.z, acc[j4 * 4 + 2]);
                acc[j4 * 4 + 3] = fmaf(s, xv.w, acc[j4 * 4 + 3]);
            }
        }
    }
    float* pf = pfeat + (size_t)b * Kk * Cc + (size_t)k * Cc + c0;
    #pragma unroll
    for (int j = 0; j < 32; ++j) atomicAdd(&pf[j], acc[j]);
}

// ---------------------------------------------------------------------------
extern "C" void kernel_launch(void* const* d_in, const int* in_sizes, int n_in,
                              void* d_out, int out_size, void* d_ws, size_t ws_size,
                              hipStream_t stream)
{
    const float* x    = (const float*)d_in[0];
    const int*   ei   = (const int*)d_in[1];     // int64 ref -> int32 on device
    const float* ew   = (const float*)d_in[2];
    const int*   mask = (const int*)d_in[3];
    const float* W1   = (const float*)d_in[4];
    const float* b1   = (const float*)d_in[5];
    const float* W2   = (const float*)d_in[6];
    const float* b2   = (const float*)d_in[7];

    float* out    = (float*)d_out;
    float* pfeat  = out;
    float* pooled = out + (size_t)Bb * Kk * Cc;
    float* pmask  = out + (size_t)Bb * Kk * Cc + (size_t)Bb * Kk * Kk;

    float* S = (float*)d_ws;                     // B*N*K f32 = 40.96 MB

    hipMemsetAsync(d_out, 0, sizeof(float) * (size_t)out_size, stream);

    k_compute_S<<<1024, 256, 0, stream>>>(x, mask, W1, b1, W2, b2, S);
    k_pmask<<<Bb, 256, 0, stream>>>(mask, pmask);
    k_pooled_edges<<<512, 256, 0, stream>>>(ei, ew, mask, S, pooled);
    k_pfeat<<<512, 256, 0, stream>>>(x, S, pfeat);
}

// Round 5
// 275.763 us; speedup vs baseline: 4.7265x; 1.9170x over previous
//
#include <hip/hip_runtime.h>

#define Bb 8
#define Nn 20000
#define Cc 128
#define Kk 64
#define Ee 320000

#define WAVES_PER_BLOCK 4
#define NODES_PER_WAVE 4

typedef __attribute__((ext_vector_type(8))) short bf16x8;
typedef __attribute__((ext_vector_type(16))) float f32x16;

__device__ __forceinline__ unsigned short f2bf(float f) {
    unsigned int u = __float_as_uint(f);
    u += 0x7FFFu + ((u >> 16) & 1u);          // round-to-nearest-even
    return (unsigned short)(u >> 16);
}

// ---------------------------------------------------------------------------
// Kernel 1: per-node MLP -> softmax -> mask  => S (B,N,K) f32  (unchanged)
// ---------------------------------------------------------------------------
__global__ __launch_bounds__(256) void k_compute_S(
    const float* __restrict__ x, const int* __restrict__ mask,
    const float* __restrict__ W1, const float* __restrict__ b1,
    const float* __restrict__ W2, const float* __restrict__ b2,
    float* __restrict__ S)
{
    __shared__ float W1s[Cc * Kk];
    __shared__ float W2s[Kk * Kk];
    __shared__ __align__(16) float xs[WAVES_PER_BLOCK][NODES_PER_WAVE * Cc];
    __shared__ __align__(16) float hs[WAVES_PER_BLOCK][NODES_PER_WAVE * Kk];

    const int tid = threadIdx.x;
    for (int i = tid; i < Cc * Kk; i += 256) W1s[i] = W1[i];
    for (int i = tid; i < Kk * Kk; i += 256) W2s[i] = W2[i];
    __syncthreads();

    const int lane = tid & 63;
    const int wid  = tid >> 6;
    const float b1k = b1[lane];
    const float b2l = b2[lane];

    const int quadsPerBatch = Nn / NODES_PER_WAVE;
    const int totalQuads = Bb * quadsPerBatch;
    const int gwave  = blockIdx.x * WAVES_PER_BLOCK + wid;
    const int nwaves = gridDim.x * WAVES_PER_BLOCK;

    for (int q = gwave; q < totalQuads; q += nwaves) {
        const int b  = q / quadsPerBatch;
        const int n0 = (q % quadsPerBatch) * NODES_PER_WAVE;
        const size_t xbase = ((size_t)b * Nn + n0) * Cc;

        {
            const float4* xg = (const float4*)(x + xbase);
            float4* xl = (float4*)xs[wid];
            #pragma unroll
            for (int i = 0; i < 2; ++i) xl[lane + 64 * i] = xg[lane + 64 * i];
        }

        float h[NODES_PER_WAVE];
        #pragma unroll
        for (int i = 0; i < NODES_PER_WAVE; ++i) h[i] = b1k;

        for (int c0 = 0; c0 < Cc; c0 += 4) {
            float4 xv[NODES_PER_WAVE];
            #pragma unroll
            for (int i = 0; i < NODES_PER_WAVE; ++i)
                xv[i] = *(const float4*)&xs[wid][i * Cc + c0];
            #pragma unroll
            for (int j = 0; j < 4; ++j) {
                const float w1 = W1s[(c0 + j) * Kk + lane];
                #pragma unroll
                for (int i = 0; i < NODES_PER_WAVE; ++i) {
                    const float xj = (j == 0) ? xv[i].x : (j == 1) ? xv[i].y
                                    : (j == 2) ? xv[i].z : xv[i].w;
                    h[i] = fmaf(xj, w1, h[i]);
                }
            }
        }
        #pragma unroll
        for (int i = 0; i < NODES_PER_WAVE; ++i)
            hs[wid][i * Kk + lane] = fmaxf(h[i], 0.f);

        float a[NODES_PER_WAVE];
        #pragma unroll
        for (int i = 0; i < NODES_PER_WAVE; ++i) a[i] = b2l;

        for (int k0 = 0; k0 < Kk; k0 += 4) {
            float4 hv[NODES_PER_WAVE];
            #pragma unroll
            for (int i = 0; i < NODES_PER_WAVE; ++i)
                hv[i] = *(const float4*)&hs[wid][i * Kk + k0];
            #pragma unroll
            for (int j = 0; j < 4; ++j) {
                const float w2 = W2s[(k0 + j) * Kk + lane];
                #pragma unroll
                for (int i = 0; i < NODES_PER_WAVE; ++i) {
                    const float hj = (j == 0) ? hv[i].x : (j == 1) ? hv[i].y
                                    : (j == 2) ? hv[i].z : hv[i].w;
                    a[i] = fmaf(hj, w2, a[i]);
                }
            }
        }

        #pragma unroll
        for (int i = 0; i < NODES_PER_WAVE; ++i) {
            float mx = a[i];
            #pragma unroll
            for (int off = 32; off >= 1; off >>= 1)
                mx = fmaxf(mx, __shfl_xor(mx, off));
            const float e = __expf(a[i] - mx);
            float sm = e;
            #pragma unroll
            for (int off = 32; off >= 1; off >>= 1)
                sm += __shfl_xor(sm, off);
            const float mv = (mask[(size_t)b * Nn + n0 + i] > 0) ? 1.f : 0.f;
            S[((size_t)b * Nn + n0 + i) * Kk + lane] = e / sm * mv;
        }
    }
}

// ---------------------------------------------------------------------------
// Kernel 2: pmask (unchanged)
// ---------------------------------------------------------------------------
__global__ __launch_bounds__(256) void k_pmask(const int* __restrict__ mask,
                                               float* __restrict__ pmask)
{
    __shared__ int s_any;
    if (threadIdx.x == 0) s_any = 0;
    __syncthreads();
    const int b = blockIdx.x;
    int any = 0;
    for (int i = threadIdx.x; i < Nn; i += blockDim.x)
        any |= (mask[(size_t)b * Nn + i] > 0) ? 1 : 0;
    if (any) atomicOr(&s_any, 1);
    __syncthreads();
    if (threadIdx.x < Kk)
        pmask[(size_t)b * Kk + threadIdx.x] = s_any ? 1.f : 0.f;
}

// ---------------------------------------------------------------------------
// Kernel 3: pooled (MFMA edge-GEMM, unchanged from R4)
// ---------------------------------------------------------------------------
__global__ __launch_bounds__(256) void k_pooled_edges(
    const int* __restrict__ ei, const float* __restrict__ ew,
    const int* __restrict__ mask, const float* __restrict__ S,
    float* __restrict__ pooled)
{
    __shared__ float tile[Kk * Kk];
    __shared__ int   qu[4][128];
    __shared__ int   qv[4][128];
    __shared__ float qw[4][128];
    __shared__ unsigned short AVb[4][1024];
    __shared__ unsigned short BUb[4][1024];

    const int tid  = threadIdx.x;
    const int lane = tid & 63;
    const int wid  = tid >> 6;

    for (int i = tid; i < Kk * Kk; i += 256) tile[i] = 0.f;
    __syncthreads();

    const int b    = blockIdx.x >> 6;
    const int slot = blockIdx.x & 63;
    const int groupsPerBatch = Ee / 64;
    const size_t eib = (size_t)b * 2 * Ee;
    const float* Sb = S + (size_t)b * Nn * Kk;
    const int*   mb = mask + (size_t)b * Nn;

    int*   quw = qu[wid];
    int*   qvw = qv[wid];
    float* qww = qw[wid];
    unsigned short* AVw = AVb[wid];
    unsigned short* BUw = BUb[wid];

    f32x16 acc00 = 0.f, acc01 = 0.f, acc10 = 0.f, acc11 = 0.f;

    const int wbase = (lane >> 5) * 512 + (lane & 31) * 8;

    auto process16 = [&](int hd) {
        asm volatile("s_waitcnt lgkmcnt(0)" ::: "memory");
        const int sl = (hd + (lane & 15)) & 127;
        const int   uu = quw[sl];
        const int   vv = qvw[sl];
        const float ww = qww[sl];
        float sv[16], su[16];
        #pragma unroll
        for (int j = 0; j < 16; ++j) {
            const int vj = __shfl(vv, j);
            const int uj = __shfl(uu, j);
            sv[j] = Sb[(size_t)vj * Kk + lane];
            su[j] = Sb[(size_t)uj * Kk + lane];
        }
        #pragma unroll
        for (int j = 0; j < 16; ++j) {
            const float wj = __shfl(ww, j);
            const int ci = wbase + (j >> 3) * 256 + (j & 7);
            AVw[ci] = f2bf(wj * sv[j]);
            BUw[ci] = f2bf(su[j]);
        }
        asm volatile("s_waitcnt lgkmcnt(0)" ::: "memory");
        const bf16x8* Af = (const bf16x8*)AVw;
        const bf16x8* Bf = (const bf16x8*)BUw;
        const bf16x8 a0 = Af[lane];
        const bf16x8 a1 = Af[64 + lane];
        const bf16x8 b0 = Bf[lane];
        const bf16x8 b1 = Bf[64 + lane];
        acc00 = __builtin_amdgcn_mfma_f32_32x32x16_bf16(a0, b0, acc00, 0, 0, 0);
        acc01 = __builtin_amdgcn_mfma_f32_32x32x16_bf16(a0, b1, acc01, 0, 0, 0);
        acc10 = __builtin_amdgcn_mfma_f32_32x32x16_bf16(a1, b0, acc10, 0, 0, 0);
        acc11 = __builtin_amdgcn_mfma_f32_32x32x16_bf16(a1, b1, acc11, 0, 0, 0);
    };

    int head = 0, count = 0;
    const int wslot = slot * 4 + wid;
    for (int g = wslot; g < groupsPerBatch; g += 256) {
        const int e0 = g * 64;
        const int   u = ei[eib + e0 + lane];
        const int   v = ei[eib + Ee + e0 + lane];
        const float w = ew[(size_t)b * Ee + e0 + lane];
        const bool valid = (mb[u] > 0) && (mb[v] > 0);
        const unsigned long long mk = __ballot(valid);
        const int myoff = __popcll(mk & ((1ull << lane) - 1ull));
        if (valid) {
            const int p = (head + count + myoff) & 127;
            quw[p] = u; qvw[p] = v; qww[p] = w;
        }
        count += (int)__popcll(mk);
        while (count >= 16) {
            process16(head);
            head = (head + 16) & 127;
            count -= 16;
        }
    }
    if (count > 0) {
        if (lane < 16 && lane >= count) {
            const int p = (head + lane) & 127;
            quw[p] = 0; qvw[p] = 0; qww[p] = 0.f;
        }
        process16(head);
    }

    const int rbase = 4 * (lane >> 5);
    const int col   = lane & 31;
    #pragma unroll
    for (int r = 0; r < 16; ++r) {
        const int row = (r & 3) + 8 * (r >> 2) + rbase;
        atomicAdd(&tile[row * Kk + col],              acc00[r]);
        atomicAdd(&tile[row * Kk + 32 + col],         acc01[r]);
        atomicAdd(&tile[(32 + row) * Kk + col],       acc10[r]);
        atomicAdd(&tile[(32 + row) * Kk + 32 + col],  acc11[r]);
    }
    __syncthreads();
    float* pb = pooled + (size_t)b * Kk * Kk;
    for (int i = tid; i < Kk * Kk; i += 256)
        atomicAdd(&pb[i], tile[i]);
}

// ---------------------------------------------------------------------------
// Kernel 4 (MFMA rewrite): pfeat[b,k,c] = sum_n S[b,n,k] * x[b,n,c]
// = per-batch 64x128 GEMM over N. No LDS, no barriers: each wave owns a
// 32-column c-quadrant, loads A(S^T)/B(x) fragments straight from global in
// fragment order (per j: lanes 0-31 row nb+j, lanes 32-63 row nb+8+j --
// two coalesced 128B segments), cvt->bf16, 2x mfma_f32_32x32x16_bf16.
// ---------------------------------------------------------------------------
__global__ __launch_bounds__(256) void k_pfeat(
    const float* __restrict__ x, const float* __restrict__ S,
    float* __restrict__ pfeat)
{
    const int tid  = threadIdx.x;
    const int lane = tid & 63;
    const int wid  = tid >> 6;
    const int b    = blockIdx.x & 7;
    const int slot = blockIdx.x >> 3;
    const int bpb  = gridDim.x >> 3;

    const float* xb  = x + (size_t)b * Nn * Cc;
    const float* Sbp = S + (size_t)b * Nn * Kk;

    const int nodeoff = (lane >> 5) * 8;     // kk fragment offset
    const int kc      = lane & 31;           // free-dim index within fragment
    const int c       = wid * 32 + kc;       // this wave's c column

    f32x16 acc0 = 0.f, acc1 = 0.f;

    const int chunks = Nn / 16;              // 1250
    for (int ch = slot; ch < chunks; ch += bpb) {
        const int nb = ch * 16 + nodeoff;
        float a0f[8], a1f[8], bff[8];
        #pragma unroll
        for (int j = 0; j < 8; ++j) {
            const size_t n = (size_t)(nb + j);
            a0f[j] = Sbp[n * Kk + kc];            // S[node][k]     (k 0-31)
            a1f[j] = Sbp[n * Kk + 32 + kc];       // S[node][k+32]
            bff[j] = xb[n * Cc + c];              // x[node][c]
        }
        bf16x8 a0, a1, bbf;
        #pragma unroll
        for (int j = 0; j < 8; ++j) {
            a0[j]  = (short)f2bf(a0f[j]);
            a1[j]  = (short)f2bf(a1f[j]);
            bbf[j] = (short)f2bf(bff[j]);
        }
        acc0 = __builtin_amdgcn_mfma_f32_32x32x16_bf16(a0, bbf, acc0, 0, 0, 0);
        acc1 = __builtin_amdgcn_mfma_f32_32x32x16_bf16(a1, bbf, acc1, 0, 0, 0);
    }

    // C/D layout (verified m74/m101): col = lane&31 (c), row = (r&3)+8*(r>>2)+4*(lane>>5) (k)
    float* pf = pfeat + (size_t)b * Kk * Cc;
    const int colc  = wid * 32 + (lane & 31);
    const int rbase = 4 * (lane >> 5);
    #pragma unroll
    for (int r = 0; r < 16; ++r) {
        const int row = (r & 3) + 8 * (r >> 2) + rbase;
        atomicAdd(&pf[row * Cc + colc],        acc0[r]);
        atomicAdd(&pf[(32 + row) * Cc + colc], acc1[r]);
    }
}

// ---------------------------------------------------------------------------
extern "C" void kernel_launch(void* const* d_in, const int* in_sizes, int n_in,
                              void* d_out, int out_size, void* d_ws, size_t ws_size,
                              hipStream_t stream)
{
    const float* x    = (const float*)d_in[0];
    const int*   ei   = (const int*)d_in[1];     // int64 ref -> int32 on device
    const float* ew   = (const float*)d_in[2];
    const int*   mask = (const int*)d_in[3];
    const float* W1   = (const float*)d_in[4];
    const float* b1   = (const float*)d_in[5];
    const float* W2   = (const float*)d_in[6];
    const float* b2   = (const float*)d_in[7];

    float* out    = (float*)d_out;
    float* pfeat  = out;
    float* pooled = out + (size_t)Bb * Kk * Cc;
    float* pmask  = out + (size_t)Bb * Kk * Cc + (size_t)Bb * Kk * Kk;

    float* S = (float*)d_ws;                     // B*N*K f32 = 40.96 MB

    hipMemsetAsync(d_out, 0, sizeof(float) * (size_t)out_size, stream);

    k_compute_S<<<1024, 256, 0, stream>>>(x, mask, W1, b1, W2, b2, S);
    k_pmask<<<Bb, 256, 0, stream>>>(mask, pmask);
    k_pooled_edges<<<512, 256, 0, stream>>>(ei, ew, mask, S, pooled);
    k_pfeat<<<512, 256, 0, stream>>>(x, S, pfeat);
}

// Round 6
// 196.755 us; speedup vs baseline: 6.6245x; 1.4016x over previous
//
#include <hip/hip_runtime.h>

#define Bb 8
#define Nn 20000
#define Cc 128
#define Kk 64
#define Ee 320000

#define WAVES_PER_BLOCK 4

typedef __attribute__((ext_vector_type(8))) short bf16x8;
typedef __attribute__((ext_vector_type(16))) float f32x16;

__device__ __forceinline__ unsigned short f2bf(float f) {
    unsigned int u = __float_as_uint(f);
    u += 0x7FFFu + ((u >> 16) & 1u);          // round-to-nearest-even
    return (unsigned short)(u >> 16);
}

// ---------------------------------------------------------------------------
// Kernel 1 (MFMA rewrite): S = softmax(relu(x@W1+b1)@W2+b2) * m
// One wave = 32 nodes. GEMM1: h^T = W1^T (A, m=k) @ x^T (B, n=node).
// GEMM2: S^T-tiles = W2^T (A, m=l) @ h^T (B, n=node), h-fragments built
// in-register from GEMM1 acc via shfl_xor(.,32) cross-half exchange.
// W1/W2 pre-converted to bf16 fragment layout in LDS (24.5 KB/block).
// ---------------------------------------------------------------------------
__global__ __launch_bounds__(256) void k_compute_S(
    const float* __restrict__ x, const int* __restrict__ mask,
    const float* __restrict__ W1, const float* __restrict__ b1,
    const float* __restrict__ W2, const float* __restrict__ b2,
    float* __restrict__ S)
{
    __shared__ unsigned short W1A[8192];   // 16 KB: [(cs*2+kh)*64+lane]*8+j
    __shared__ unsigned short W2A[4096];   //  8 KB: [(ks*2+lh)*64+lane]*8+j
    __shared__ float b1s[Kk];
    __shared__ float b2s[Kk];

    const int tid = threadIdx.x;

    // ---- prologue: weights -> bf16 fragment layout in LDS ----
    for (int idx = tid; idx < 8192; idx += 256) {
        const int j  = idx & 7;
        const int ln = (idx >> 3) & 63;
        const int t  = idx >> 9;            // 0..15
        const int kh = t & 1;
        const int cs = t >> 1;              // 0..7
        W1A[idx] = f2bf(W1[(cs * 16 + (ln >> 5) * 8 + j) * Kk + kh * 32 + (ln & 31)]);
    }
    for (int idx = tid; idx < 4096; idx += 256) {
        const int j  = idx & 7;
        const int ln = (idx >> 3) & 63;
        const int t  = idx >> 9;            // 0..7
        const int lh = t & 1;
        const int ks = t >> 1;              // 0..3
        W2A[idx] = f2bf(W2[(ks * 16 + (ln >> 5) * 8 + j) * Kk + lh * 32 + (ln & 31)]);
    }
    if (tid < Kk) { b1s[tid] = b1[tid]; b2s[tid] = b2[tid]; }
    __syncthreads();

    const int lane = tid & 63;
    const int wid  = tid >> 6;
    const int hsel = lane >> 5;             // lane half
    const int m32  = lane & 31;

    const int wc = blockIdx.x * WAVES_PER_BLOCK + wid;  // 0..4999 (grid=1250)
    const int chunksPerBatch = Nn / 32;     // 625
    const int b  = wc / chunksPerBatch;
    const int n0 = (wc % chunksPerBatch) * 32;
    const int nd = n0 + m32;                // this lane's node (column)

    // ---- GEMM1: accA (k 0..31), accB (k 32..63); col = node ----
    const float* xrow = x + ((size_t)b * Nn + nd) * Cc;
    f32x16 accA = 0.f, accB = 0.f;
    #pragma unroll
    for (int cs = 0; cs < 8; ++cs) {
        const float4 f0 = *(const float4*)&xrow[cs * 16 + hsel * 8];
        const float4 f1 = *(const float4*)&xrow[cs * 16 + hsel * 8 + 4];
        bf16x8 xa;
        xa[0] = (short)f2bf(f0.x); xa[1] = (short)f2bf(f0.y);
        xa[2] = (short)f2bf(f0.z); xa[3] = (short)f2bf(f0.w);
        xa[4] = (short)f2bf(f1.x); xa[5] = (short)f2bf(f1.y);
        xa[6] = (short)f2bf(f1.z); xa[7] = (short)f2bf(f1.w);
        const bf16x8 w1h0 = *(const bf16x8*)&W1A[((cs * 2 + 0) * 64 + lane) * 8];
        const bf16x8 w1h1 = *(const bf16x8*)&W1A[((cs * 2 + 1) * 64 + lane) * 8];
        accA = __builtin_amdgcn_mfma_f32_32x32x16_bf16(w1h0, xa, accA, 0, 0, 0);
        accB = __builtin_amdgcn_mfma_f32_32x32x16_bf16(w1h1, xa, accB, 0, 0, 0);
    }

    // ---- h extraction (+b1, relu) and GEMM2, fused per K-step ----
    f32x16 accS0 = 0.f, accS1 = 0.f;

#define EXTRACT_GEMM2(KS, ACC)                                                 \
    {                                                                          \
        bf16x8 hf;                                                             \
        _Pragma("unroll")                                                      \
        for (int jj = 0; jj < 4; ++jj) {                                       \
            const int c0 = jj + 8 * ((KS) & 1);                                \
            const float own  = hsel ? (ACC)[c0 + 4] : (ACC)[c0];               \
            const float send = hsel ? (ACC)[c0]     : (ACC)[c0 + 4];           \
            const float sw   = __shfl_xor(send, 32);                           \
            const float vlo  = hsel ? sw  : own;   /* j = jj   */              \
            const float vhi  = hsel ? own : sw;    /* j = jj+4 */              \
            const int klo = (KS) * 16 + 8 * hsel + jj;                         \
            hf[jj]     = (short)f2bf(fmaxf(vlo + b1s[klo], 0.f));              \
            hf[jj + 4] = (short)f2bf(fmaxf(vhi + b1s[klo + 4], 0.f));          \
        }                                                                      \
        const bf16x8 w2l0 = *(const bf16x8*)&W2A[(((KS) * 2 + 0) * 64 + lane) * 8]; \
        const bf16x8 w2l1 = *(const bf16x8*)&W2A[(((KS) * 2 + 1) * 64 + lane) * 8]; \
        accS0 = __builtin_amdgcn_mfma_f32_32x32x16_bf16(w2l0, hf, accS0, 0, 0, 0); \
        accS1 = __builtin_amdgcn_mfma_f32_32x32x16_bf16(w2l1, hf, accS1, 0, 0, 0); \
    }

    EXTRACT_GEMM2(0, accA)
    EXTRACT_GEMM2(1, accA)
    EXTRACT_GEMM2(2, accB)
    EXTRACT_GEMM2(3, accB)
#undef EXTRACT_GEMM2

    // ---- bias2 + softmax over l (32 own values + cross-half combine) ----
    float z0[16], z1[16];
    float mm = -1e30f;
    #pragma unroll
    for (int r = 0; r < 16; ++r) {
        const int l = (r & 3) + 8 * (r >> 2) + 4 * hsel;
        z0[r] = accS0[r] + b2s[l];
        z1[r] = accS1[r] + b2s[l + 32];
        mm = fmaxf(mm, fmaxf(z0[r], z1[r]));
    }
    mm = fmaxf(mm, __shfl_xor(mm, 32));
    float ssum = 0.f;
    #pragma unroll
    for (int r = 0; r < 16; ++r) {
        z0[r] = __expf(z0[r] - mm);
        z1[r] = __expf(z1[r] - mm);
        ssum += z0[r] + z1[r];
    }
    ssum += __shfl_xor(ssum, 32);
    const int   mv = mask[(size_t)b * Nn + nd];
    const float rs = (mv > 0) ? (1.f / ssum) : 0.f;

    // ---- store: reg-contiguous groups of 4 consecutive l ----
    float* Srow = S + ((size_t)b * Nn + nd) * Kk;
    #pragma unroll
    for (int g = 0; g < 4; ++g) {
        float4 s0, s1;
        s0.x = z0[4 * g + 0] * rs; s0.y = z0[4 * g + 1] * rs;
        s0.z = z0[4 * g + 2] * rs; s0.w = z0[4 * g + 3] * rs;
        s1.x = z1[4 * g + 0] * rs; s1.y = z1[4 * g + 1] * rs;
        s1.z = z1[4 * g + 2] * rs; s1.w = z1[4 * g + 3] * rs;
        *(float4*)&Srow[8 * g + 4 * hsel]      = s0;
        *(float4*)&Srow[8 * g + 4 * hsel + 32] = s1;
    }
}

// ---------------------------------------------------------------------------
// Kernel 2: pmask (unchanged)
// ---------------------------------------------------------------------------
__global__ __launch_bounds__(256) void k_pmask(const int* __restrict__ mask,
                                               float* __restrict__ pmask)
{
    __shared__ int s_any;
    if (threadIdx.x == 0) s_any = 0;
    __syncthreads();
    const int b = blockIdx.x;
    int any = 0;
    for (int i = threadIdx.x; i < Nn; i += blockDim.x)
        any |= (mask[(size_t)b * Nn + i] > 0) ? 1 : 0;
    if (any) atomicOr(&s_any, 1);
    __syncthreads();
    if (threadIdx.x < Kk)
        pmask[(size_t)b * Kk + threadIdx.x] = s_any ? 1.f : 0.f;
}

// ---------------------------------------------------------------------------
// Kernel 3: pooled (MFMA edge-GEMM, unchanged from R4)
// ---------------------------------------------------------------------------
__global__ __launch_bounds__(256) void k_pooled_edges(
    const int* __restrict__ ei, const float* __restrict__ ew,
    const int* __restrict__ mask, const float* __restrict__ S,
    float* __restrict__ pooled)
{
    __shared__ float tile[Kk * Kk];
    __shared__ int   qu[4][128];
    __shared__ int   qv[4][128];
    __shared__ float qw[4][128];
    __shared__ unsigned short AVb[4][1024];
    __shared__ unsigned short BUb[4][1024];

    const int tid  = threadIdx.x;
    const int lane = tid & 63;
    const int wid  = tid >> 6;

    for (int i = tid; i < Kk * Kk; i += 256) tile[i] = 0.f;
    __syncthreads();

    const int b    = blockIdx.x >> 6;
    const int slot = blockIdx.x & 63;
    const int groupsPerBatch = Ee / 64;
    const size_t eib = (size_t)b * 2 * Ee;
    const float* Sb = S + (size_t)b * Nn * Kk;
    const int*   mb = mask + (size_t)b * Nn;

    int*   quw = qu[wid];
    int*   qvw = qv[wid];
    float* qww = qw[wid];
    unsigned short* AVw = AVb[wid];
    unsigned short* BUw = BUb[wid];

    f32x16 acc00 = 0.f, acc01 = 0.f, acc10 = 0.f, acc11 = 0.f;

    const int wbase = (lane >> 5) * 512 + (lane & 31) * 8;

    auto process16 = [&](int hd) {
        asm volatile("s_waitcnt lgkmcnt(0)" ::: "memory");
        const int sl = (hd + (lane & 15)) & 127;
        const int   uu = quw[sl];
        const int   vv = qvw[sl];
        const float ww = qww[sl];
        float sv[16], su[16];
        #pragma unroll
        for (int j = 0; j < 16; ++j) {
            const int vj = __shfl(vv, j);
            const int uj = __shfl(uu, j);
            sv[j] = Sb[(size_t)vj * Kk + lane];
            su[j] = Sb[(size_t)uj * Kk + lane];
        }
        #pragma unroll
        for (int j = 0; j < 16; ++j) {
            const float wj = __shfl(ww, j);
            const int ci = wbase + (j >> 3) * 256 + (j & 7);
            AVw[ci] = f2bf(wj * sv[j]);
            BUw[ci] = f2bf(su[j]);
        }
        asm volatile("s_waitcnt lgkmcnt(0)" ::: "memory");
        const bf16x8* Af = (const bf16x8*)AVw;
        const bf16x8* Bf = (const bf16x8*)BUw;
        const bf16x8 a0 = Af[lane];
        const bf16x8 a1 = Af[64 + lane];
        const bf16x8 b0 = Bf[lane];
        const bf16x8 b1 = Bf[64 + lane];
        acc00 = __builtin_amdgcn_mfma_f32_32x32x16_bf16(a0, b0, acc00, 0, 0, 0);
        acc01 = __builtin_amdgcn_mfma_f32_32x32x16_bf16(a0, b1, acc01, 0, 0, 0);
        acc10 = __builtin_amdgcn_mfma_f32_32x32x16_bf16(a1, b0, acc10, 0, 0, 0);
        acc11 = __builtin_amdgcn_mfma_f32_32x32x16_bf16(a1, b1, acc11, 0, 0, 0);
    };

    int head = 0, count = 0;
    const int wslot = slot * 4 + wid;
    for (int g = wslot; g < groupsPerBatch; g += 256) {
        const int e0 = g * 64;
        const int   u = ei[eib + e0 + lane];
        const int   v = ei[eib + Ee + e0 + lane];
        const float w = ew[(size_t)b * Ee + e0 + lane];
        const bool valid = (mb[u] > 0) && (mb[v] > 0);
        const unsigned long long mk = __ballot(valid);
        const int myoff = __popcll(mk & ((1ull << lane) - 1ull));
        if (valid) {
            const int p = (head + count + myoff) & 127;
            quw[p] = u; qvw[p] = v; qww[p] = w;
        }
        count += (int)__popcll(mk);
        while (count >= 16) {
            process16(head);
            head = (head + 16) & 127;
            count -= 16;
        }
    }
    if (count > 0) {
        if (lane < 16 && lane >= count) {
            const int p = (head + lane) & 127;
            quw[p] = 0; qvw[p] = 0; qww[p] = 0.f;
        }
        process16(head);
    }

    const int rbase = 4 * (lane >> 5);
    const int col   = lane & 31;
    #pragma unroll
    for (int r = 0; r < 16; ++r) {
        const int row = (r & 3) + 8 * (r >> 2) + rbase;
        atomicAdd(&tile[row * Kk + col],              acc00[r]);
        atomicAdd(&tile[row * Kk + 32 + col],         acc01[r]);
        atomicAdd(&tile[(32 + row) * Kk + col],       acc10[r]);
        atomicAdd(&tile[(32 + row) * Kk + 32 + col],  acc11[r]);
    }
    __syncthreads();
    float* pb = pooled + (size_t)b * Kk * Kk;
    for (int i = tid; i < Kk * Kk; i += 256)
        atomicAdd(&pb[i], tile[i]);
}

// ---------------------------------------------------------------------------
// Kernel 4: pfeat (MFMA, unchanged from R5)
// ---------------------------------------------------------------------------
__global__ __launch_bounds__(256) void k_pfeat(
    const float* __restrict__ x, const float* __restrict__ S,
    float* __restrict__ pfeat)
{
    const int tid  = threadIdx.x;
    const int lane = tid & 63;
    const int wid  = tid >> 6;
    const int b    = blockIdx.x & 7;
    const int slot = blockIdx.x >> 3;
    const int bpb  = gridDim.x >> 3;

    const float* xb  = x + (size_t)b * Nn * Cc;
    const float* Sbp = S + (size_t)b * Nn * Kk;

    const int nodeoff = (lane >> 5) * 8;
    const int kc      = lane & 31;
    const int c       = wid * 32 + kc;

    f32x16 acc0 = 0.f, acc1 = 0.f;

    const int chunks = Nn / 16;
    for (int ch = slot; ch < chunks; ch += bpb) {
        const int nb = ch * 16 + nodeoff;
        float a0f[8], a1f[8], bff[8];
        #pragma unroll
        for (int j = 0; j < 8; ++j) {
            const size_t n = (size_t)(nb + j);
            a0f[j] = Sbp[n * Kk + kc];
            a1f[j] = Sbp[n * Kk + 32 + kc];
            bff[j] = xb[n * Cc + c];
        }
        bf16x8 a0, a1, bbf;
        #pragma unroll
        for (int j = 0; j < 8; ++j) {
            a0[j]  = (short)f2bf(a0f[j]);
            a1[j]  = (short)f2bf(a1f[j]);
            bbf[j] = (short)f2bf(bff[j]);
        }
        acc0 = __builtin_amdgcn_mfma_f32_32x32x16_bf16(a0, bbf, acc0, 0, 0, 0);
        acc1 = __builtin_amdgcn_mfma_f32_32x32x16_bf16(a1, bbf, acc1, 0, 0, 0);
    }

    float* pf = pfeat + (size_t)b * Kk * Cc;
    const int colc  = wid * 32 + (lane & 31);
    const int rbase = 4 * (lane >> 5);
    #pragma unroll
    for (int r = 0; r < 16; ++r) {
        const int row = (r & 3) + 8 * (r >> 2) + rbase;
        atomicAdd(&pf[row * Cc + colc],        acc0[r]);
        atomicAdd(&pf[(32 + row) * Cc + colc], acc1[r]);
    }
}

// ---------------------------------------------------------------------------
extern "C" void kernel_launch(void* const* d_in, const int* in_sizes, int n_in,
                              void* d_out, int out_size, void* d_ws, size_t ws_size,
                              hipStream_t stream)
{
    const float* x    = (const float*)d_in[0];
    const int*   ei   = (const int*)d_in[1];     // int64 ref -> int32 on device
    const float* ew   = (const float*)d_in[2];
    const int*   mask = (const int*)d_in[3];
    const float* W1   = (const float*)d_in[4];
    const float* b1   = (const float*)d_in[5];
    const float* W2   = (const float*)d_in[6];
    const float* b2   = (const float*)d_in[7];

    float* out    = (float*)d_out;
    float* pfeat  = out;
    float* pooled = out + (size_t)Bb * Kk * Cc;
    float* pmask  = out + (size_t)Bb * Kk * Cc + (size_t)Bb * Kk * Kk;

    float* S = (float*)d_ws;                     // B*N*K f32 = 40.96 MB

    hipMemsetAsync(d_out, 0, sizeof(float) * (size_t)out_size, stream);

    k_compute_S<<<1250, 256, 0, stream>>>(x, mask, W1, b1, W2, b2, S);
    k_pmask<<<Bb, 256, 0, stream>>>(mask, pmask);
    k_pooled_edges<<<512, 256, 0, stream>>>(ei, ew, mask, S, pooled);
    k_pfeat<<<512, 256, 0, stream>>>(x, S, pfeat);
}